// Round 7
// baseline (88.729 us; speedup 1.0000x reference)
//
#include <hip/hip_runtime.h>

// Problem constants (fixed by setup_inputs).
constexpr int L  = 512;   // sequence length
constexpr int CS = 384;   // c_s
constexpr int CH = 32;    // c_h
constexpr int CZ = 128;   // c_z
constexpr float LN_EPS = 1e-5f;

typedef float f4 __attribute__((ext_vector_type(4)));

// ---------------------------------------------------------------------------
// Kernel 1: LayerNorm over c_s + dual projection (w1/b1, w2/b2) + mask.
// ---------------------------------------------------------------------------
__global__ __launch_bounds__(256) void k_ln_proj(
    const float* __restrict__ s, const int* __restrict__ mask,
    const float* __restrict__ ln_scale, const float* __restrict__ ln_bias,
    const float* __restrict__ w1, const float* __restrict__ b1,
    const float* __restrict__ w2, const float* __restrict__ b2,
    float* __restrict__ a, float* __restrict__ b)
{
    __shared__ float sn_lds[4][CS];
    const int wave = threadIdx.x >> 6;
    const int lane = threadIdx.x & 63;
    const int row  = blockIdx.x * 4 + wave;

    const float* srow = s + row * CS;
    float v[6];
    float sum = 0.f, sumsq = 0.f;
#pragma unroll
    for (int q = 0; q < 6; ++q) {
        v[q] = srow[lane + 64 * q];
        sum   += v[q];
        sumsq += v[q] * v[q];
    }
#pragma unroll
    for (int off = 32; off; off >>= 1) {
        sum   += __shfl_xor(sum, off);
        sumsq += __shfl_xor(sumsq, off);
    }
    const float mu   = sum * (1.f / CS);
    const float var  = sumsq * (1.f / CS) - mu * mu;
    const float rstd = rsqrtf(var + LN_EPS);
#pragma unroll
    for (int q = 0; q < 6; ++q) {
        const int k = lane + 64 * q;
        sn_lds[wave][k] = (v[q] - mu) * rstd * ln_scale[k] + ln_bias[k];
    }
    __syncthreads();

    const int c    = lane & 31;
    const int half = lane >> 5;
    const float* W  = half ? w2 : w1;
    const float* Bv = half ? b2 : b1;
    float acc = 0.f;
#pragma unroll 4
    for (int k = 0; k < CS; ++k)
        acc += sn_lds[wave][k] * W[k * CH + c];
    const float m = (float)mask[row];
    const float outv = (acc + Bv[c]) * m;
    (half ? b : a)[row * CH + c] = outv;
}

// ---------------------------------------------------------------------------
// Kernel 2: T[j][c][z] = sum_e b[j][e] * w_out[(c*CH+e)*CZ + z]  (8 MB in ws).
// ---------------------------------------------------------------------------
__global__ __launch_bounds__(512) void k_T(
    const float* __restrict__ b, const float* __restrict__ w_out,
    float* __restrict__ T)
{
    const int czg = blockIdx.x & 7;
    const int jg  = blockIdx.x >> 3;
    const int t   = threadIdx.x;
    const int idx = czg * 512 + t;
    const int c   = idx >> 7;
    const int z   = idx & (CZ - 1);

    float w[CH];
    const float* wp = w_out + (size_t)(c * CH) * CZ + z;
#pragma unroll
    for (int e = 0; e < CH; ++e) w[e] = wp[e * CZ];

    __shared__ float b_lds[64][CH];
    ((float4*)b_lds)[t] = ((const float4*)(b + (size_t)jg * 64 * CH))[t];
    __syncthreads();

    float* Tp = T + (size_t)(jg * 64) * (CH * CZ) + idx;
#pragma unroll 4
    for (int jj = 0; jj < 64; ++jj) {
        float acc = 0.f;
#pragma unroll
        for (int e = 0; e < CH; ++e) acc += b_lds[jj][e] * w[e];
        Tp[(size_t)jj * (CH * CZ)] = acc;
    }
}

// ---------------------------------------------------------------------------
// Kernel 3: z[i,j,:] = a[i,:] @ T[j,:,:] + b_out.
// XCD-aligned row assembly:
//   i0 = (bid & 7) * 64   -> XCD x (round-robin dispatch) owns i-group x;
//   j0 = (bid >> 3) * 16  -> its 32 co-XCD blocks cover j-tiles 0..31.
//   At each i-step, the 32 blocks of one XCD collectively write ONE fully
//   contiguous 256 KB output row (same-XCD blocks stay near-lockstep), so
//   the memory controllers see ~8 concurrent linear row-streams instead of
//   256 scattered 8 KB islands -> DRAM page-hit recovery.
// Lane owns a z-quad; wave covers a j-pair; T[j] quad-column in 128 VGPRs
// reused over 64 i's; a-rows broadcast from LDS; nt f4 stores; per-step
// raw s_barrier (no vmcnt drain) keeps waves aligned.
// T re-reads across XCDs are served by L3 (T written by k_T, 8 MB << 256 MB).
// ---------------------------------------------------------------------------
__global__ __launch_bounds__(512, 1) void k_main(
    const float* __restrict__ a, const float* __restrict__ T,
    const float* __restrict__ b_out, float* __restrict__ out)
{
    __shared__ float a_lds[64][CH];    // 8 KB

    const int bid  = blockIdx.x;
    const int i0   = (bid & 7) * 64;   // XCD-aligned i-group
    const int j0   = (bid >> 3) * 16;  // j-tile of 16
    const int t    = threadIdx.x;
    const int wave = t >> 6;
    const int lane = t & 63;
    const int half = lane >> 5;        // 0: even j, 1: odd j
    const int lz   = lane & 31;        // z-quad index (z = 4*lz)
    const int j    = j0 + 2 * wave + half;

    // Stage a-tile: 2048 floats, 512 threads x float4.
    ((float4*)a_lds)[t] = ((const float4*)(a + (size_t)i0 * CH))[t];

    // T[j] quad-column for this lane: 128 VGPRs.
    f4 T4[CH];
    const f4* Tj = (const f4*)(T + (size_t)j * (CH * CZ)) + lz;
#pragma unroll
    for (int c = 0; c < CH; ++c)
        T4[c] = Tj[c * (CZ / 4)];

    const f4 bo = ((const f4*)b_out)[lz];
    float* op = out + (size_t)i0 * (L * CZ) + (size_t)j * CZ + 4 * lz;

    __syncthreads();

    for (int ii = 0; ii < 64; ++ii) {
        __builtin_amdgcn_s_barrier();   // lockstep only; no vmcnt drain
        const f4* ap = (const f4*)&a_lds[ii][0];
        f4 acc = bo;
#pragma unroll
        for (int q = 0; q < 8; ++q) {
            const f4 r = ap[q];
            acc += r.x * T4[4 * q + 0];
            acc += r.y * T4[4 * q + 1];
            acc += r.z * T4[4 * q + 2];
            acc += r.w * T4[4 * q + 3];
        }
        __builtin_nontemporal_store(acc, (f4*)(op + (size_t)ii * (L * CZ)));
    }
}

// ---------------------------------------------------------------------------
extern "C" void kernel_launch(void* const* d_in, const int* in_sizes, int n_in,
                              void* d_out, int out_size, void* d_ws, size_t ws_size,
                              hipStream_t stream) {
    const float* s        = (const float*)d_in[0];
    const int*   mask     = (const int*)d_in[1];
    const float* ln_scale = (const float*)d_in[2];
    const float* ln_bias  = (const float*)d_in[3];
    const float* w1       = (const float*)d_in[4];
    const float* b1       = (const float*)d_in[5];
    const float* w2       = (const float*)d_in[6];
    const float* b2       = (const float*)d_in[7];
    const float* w_out    = (const float*)d_in[8];
    const float* b_out    = (const float*)d_in[9];
    float* out = (float*)d_out;

    // Workspace: a [512*32], b [512*32], T [512*32*128]  (8.125 MB total).
    float* a = (float*)d_ws;
    float* b = a + L * CH;
    float* T = b + L * CH;

    k_ln_proj<<<L / 4, 256, 0, stream>>>(s, mask, ln_scale, ln_bias,
                                         w1, b1, w2, b2, a, b);
    k_T<<<L / 8, 512, 0, stream>>>(b, w_out, T);
    k_main<<<256, 512, 0, stream>>>(a, T, b_out, out);
}